// Round 19
// baseline (114.203 us; speedup 1.0000x reference)
//
#include <hip/hip_runtime.h>
#include <hip/hip_bf16.h>

// ---------------------------------------------------------------------------
// MHSA: x[2,2048,1024] f32, Wq/Wk/Wv/Wo[1024,1024] f32 -> out[2,2048,1024] f32.
// Internal bf16. Pipeline (R18 + dbuf-pairwise attn + XCD-chunked QKV):
//   1) convert: x -> xb (bf16 in d_out[0:8MB]); W* -> wb (ws)
//   2) fused QKV GEMM: BK=64 single-buffer, XOR-swizzled gload staging,
//      1-D grid 768 with XCD-chunked mapping (each XCD owns 3 B-panels).
//   3) causal flash attention: 2 waves / 64 q-rows; pairwise compute from
//      reg-held frags; LDS DOUBLE-buffer only (32 KB -> 4 blocks/CU):
//      read(t,t+1) -> barrier -> ISSUE(t+2,t+3 same bufs) -> compute pair ->
//      vmcnt(0)+barrier. Fixed-shift softmax, permlane32_swap, perm-pack.
//   4) Wo GEMM (R16): 64x128 tiles (512 blocks = 2/CU).
// ws (shorts): wb[4x1M] Q[4M] K[4M] VtG[4M] = 32 MB. attn out aliases Q.
// ---------------------------------------------------------------------------

#define DEVI __device__ __forceinline__

typedef __bf16 bf16x8 __attribute__((ext_vector_type(8)));
typedef short  short8 __attribute__((ext_vector_type(8)));
typedef float  f32x4  __attribute__((ext_vector_type(4)));
typedef float  f32x16 __attribute__((ext_vector_type(16)));
typedef unsigned int u32x4 __attribute__((ext_vector_type(4)));

DEVI short f2bfs(float f) {
    __hip_bfloat16 h = __float2bfloat16(f);
    return __builtin_bit_cast(short, h);
}
DEVI unsigned pack2rb(float a, float b) {
    const unsigned ua = __builtin_bit_cast(unsigned, a) + 0x8000u;
    const unsigned ub = __builtin_bit_cast(unsigned, b) + 0x8000u;
    return __builtin_amdgcn_perm(ub, ua, 0x07060302u);
}
DEVI bf16x8 ld8(const short* p) {
    return __builtin_bit_cast(bf16x8, *(const short8*)p);
}
DEVI void gload16(const void* g, void* lds) {
    __builtin_amdgcn_global_load_lds(
        (const __attribute__((address_space(1))) void*)g,
        (__attribute__((address_space(3))) void*)lds, 16, 0, 0);
}
DEVI void plswap(unsigned& a, unsigned& b) {
    asm volatile("v_permlane32_swap_b32 %0, %1" : "+v"(a), "+v"(b));
}
// XOR-swizzled LDS read address for [R][64] bf16 tiles: byte ^= (row&7)<<4.
DEVI const short* lds_swc(const short* base, int row, int col) {
    return (const short*)((const char*)base + (((row << 7) + (col << 1)) ^ ((row & 7) << 4)));
}

#if defined(__has_builtin)
#if __has_builtin(__builtin_amdgcn_exp2f)
#define HAVE_EXP2 1
#endif
#endif
DEVI float ex2(float x) {
#ifdef HAVE_EXP2
    return __builtin_amdgcn_exp2f(x);
#else
    return __expf(x * 0.69314718055994531f);
#endif
}
#define CEXP 0.18033688011112042f
#define MCF  (64.0f * CEXP)   // fixed softmax shift (raw-score domain)

// ---------------------------------------------------------------------------
// f32 -> bf16 convert, 1-D exact grid.
// ---------------------------------------------------------------------------
__global__ __launch_bounds__(256) void convert_kernel(
    const float* __restrict__ x, const float* __restrict__ Wq,
    const float* __restrict__ Wk, const float* __restrict__ Wv,
    const float* __restrict__ Wo, short* __restrict__ xb, short* __restrict__ wb) {
    const int bid = blockIdx.x;
    const float* src;
    short* dst;
    int i8;
    if (bid < 2048) {
        src = x; dst = xb;
        i8 = (bid * 256 + threadIdx.x) * 8;
    } else {
        const int w = bid - 2048;
        const int z = w >> 9;
        src = (z == 0) ? Wq : (z == 1) ? Wk : (z == 2) ? Wv : Wo;
        dst = wb + (size_t)z * 1048576;
        i8 = (((w & 511) * 256) + threadIdx.x) * 8;
    }
    float4 a = ((const float4*)(src + i8))[0];
    float4 b = ((const float4*)(src + i8))[1];
    short8 t;
    t[0] = f2bfs(a.x); t[1] = f2bfs(a.y); t[2] = f2bfs(a.z); t[3] = f2bfs(a.w);
    t[4] = f2bfs(b.x); t[5] = f2bfs(b.y); t[6] = f2bfs(b.z); t[7] = f2bfs(b.w);
    *(short8*)(dst + i8) = t;
}

// ---------------------------------------------------------------------------
// bf16 NT-GEMM K-loop (R16): BK=64, single-buffer, XOR-swizzled staging.
// ---------------------------------------------------------------------------
template <int BM, int BN, int MF, int NF, int WN>
DEVI void gemm_kloop64(const short* __restrict__ A, const short* __restrict__ B,
                       short* As, short* Bs, int wid, int lane, f32x4 acc[MF][NF]) {
    const int l15 = lane & 15, l4 = lane >> 4;
    const int wm = wid / WN, wn = wid % WN;
    const int rowc = lane >> 3;
    const int gcol = ((lane & 7) ^ rowc) * 8;
    constexpr int NCHA = BM / 8, NCHB = BN / 8;
#pragma unroll 1
    for (int k0 = 0; k0 < 1024; k0 += 64) {
        __syncthreads();
#pragma unroll
        for (int c = wid; c < NCHA; c += 4)
            gload16(A + (size_t)(c * 8 + rowc) * 1024 + k0 + gcol, As + c * 512);
#pragma unroll
        for (int c = wid; c < NCHB; c += 4)
            gload16(B + (size_t)(c * 8 + rowc) * 1024 + k0 + gcol, Bs + c * 512);
        __syncthreads();
#pragma unroll
        for (int kk = 0; kk < 2; ++kk) {
            bf16x8 af[MF], bf[NF];
#pragma unroll
            for (int m = 0; m < MF; ++m) {
                const int row = wm * (MF * 16) + m * 16 + l15;
                af[m] = ld8(As + row * 64 + (((kk * 4 + l4) ^ (row & 7)) * 8));
            }
#pragma unroll
            for (int n = 0; n < NF; ++n) {
                const int row = wn * (NF * 16) + n * 16 + l15;
                bf[n] = ld8(Bs + row * 64 + (((kk * 4 + l4) ^ (row & 7)) * 8));
            }
#pragma unroll
            for (int m = 0; m < MF; ++m)
#pragma unroll
                for (int n = 0; n < NF; ++n)
                    acc[m][n] = __builtin_amdgcn_mfma_f32_16x16x32_bf16(af[m], bf[n], acc[m][n], 0, 0, 0);
        }
    }
}

// ---------------------------------------------------------------------------
// Fused QKV projection, XCD-chunked 1-D grid (768 blocks):
//   xcd = bid&7 owns y-panels {3*xcd .. 3*xcd+2}; idx>>3 gives (ypos, xtile).
// Each XCD's B working set = 3 panels = 768 KB (L2-resident).
// ---------------------------------------------------------------------------
__global__ __launch_bounds__(256) void gemm_qkv_kernel(
    const short* __restrict__ xb, const short* __restrict__ wb,
    short* __restrict__ Qo, short* __restrict__ Ko, short* __restrict__ VtG) {
    __shared__ short As[8192], Bs[8192];
    const int tid = threadIdx.x, lane = tid & 63, wid = tid >> 6;
    const int l15 = lane & 15, l4 = lane >> 4;
    const int wm = wid >> 1, wn = wid & 1;
    const int bid = blockIdx.x;
    const int xcd = bid & 7, idx = bid >> 3;     // idx 0..95
    const int y = xcd * 3 + (idx >> 5);          // 0..23
    const int xtile = idx & 31;                  // 0..31
    const int wsel = y >> 3;
    const int row0 = xtile * 128, col0 = (y & 7) * 128;

    f32x4 acc[4][4] = {};
    gemm_kloop64<128, 128, 4, 4, 2>(
        xb + (size_t)row0 * 1024,
        wb + (size_t)wsel * 1048576 + (size_t)col0 * 1024,
        As, Bs, wid, lane, acc);

    if (wsel == 2) {
#pragma unroll
        for (int m = 0; m < 4; ++m)
#pragma unroll
            for (int n = 0; n < 4; ++n)
#pragma unroll
                for (int j = 0; j < 4; ++j) {
                    int row = row0 + wm * 64 + m * 16 + l4 * 4 + j;
                    int col = col0 + wn * 64 + n * 16 + l15;
                    VtG[(size_t)col * 4096 + row] = f2bfs(acc[m][n][j]);
                }
    } else {
        short* C = (wsel == 0) ? Qo : Ko;
#pragma unroll
        for (int m = 0; m < 4; ++m)
#pragma unroll
            for (int n = 0; n < 4; ++n)
#pragma unroll
                for (int j = 0; j < 4; ++j) {
                    int row = row0 + wm * 64 + m * 16 + l4 * 4 + j;
                    int col = col0 + wn * 64 + n * 16 + l15;
                    C[(size_t)row * 1024 + col] = f2bfs(acc[m][n][j]);
                }
    }
}

// ---------------------------------------------------------------------------
// Output projection (R16): 64x128 tiles (512 blocks = 2/CU), BK=64.
// ---------------------------------------------------------------------------
__global__ __launch_bounds__(256) void gemm_wo_kernel(
    const short* __restrict__ Ao, const short* __restrict__ Wob,
    float* __restrict__ Cout) {
    __shared__ short As[4096], Bs[8192];
    const int tid = threadIdx.x, lane = tid & 63, wid = tid >> 6;
    const int l15 = lane & 15, l4 = lane >> 4;
    const int wn = wid;
    const int row0 = blockIdx.x * 64, col0 = blockIdx.y * 128;

    f32x4 acc[4][2] = {};
    gemm_kloop64<64, 128, 4, 2, 4>(
        Ao + (size_t)row0 * 1024, Wob + (size_t)col0 * 1024,
        As, Bs, wid, lane, acc);

#pragma unroll
    for (int m = 0; m < 4; ++m)
#pragma unroll
        for (int n = 0; n < 2; ++n)
#pragma unroll
            for (int j = 0; j < 4; ++j) {
                const int row = row0 + m * 16 + l4 * 4 + j;
                const int col = col0 + wn * 32 + n * 16 + l15;
                Cout[(size_t)row * 1024 + col] = acc[m][n][j];
            }
}

// ---------------------------------------------------------------------------
// Read the 16 MFMA fragments of one KV tile from (swizzled) LDS into regs.
// ---------------------------------------------------------------------------
DEVI void read_frags(const short* Ks, const short* Vts, int l31, int hi,
                     bf16x8 kf[8], bf16x8 vb[8]) {
#pragma unroll
    for (int ds = 0; ds < 4; ++ds) {
        kf[ds]     = ld8(lds_swc(Ks, l31,      ds * 16 + hi * 8));
        kf[4 + ds] = ld8(lds_swc(Ks, 32 + l31, ds * 16 + hi * 8));
    }
#pragma unroll
    for (int c = 0; c < 2; ++c) {
        vb[c * 4 + 0] = ld8(lds_swc(Vts, l31,      c * 32 + hi * 8));
        vb[c * 4 + 1] = ld8(lds_swc(Vts, 32 + l31, c * 32 + hi * 8));
        vb[c * 4 + 2] = ld8(lds_swc(Vts, l31,      c * 32 + 16 + hi * 8));
        vb[c * 4 + 3] = ld8(lds_swc(Vts, 32 + l31, c * 32 + 16 + hi * 8));
    }
}

// ---------------------------------------------------------------------------
// One KV tile from register frags, fixed-shift softmax (R16, verified).
// ---------------------------------------------------------------------------
template <bool DIAG>
DEVI void attn_tile_r(int kv0, const bf16x8 kf[8], const bf16x8 vb[8],
                      const bf16x8 qf[4], f32x16& o0, f32x16& o1,
                      float& l, int qrow, int hi) {
    f32x16 s0 = 0.0f, s1 = 0.0f;
    __builtin_amdgcn_s_setprio(1);
#pragma unroll
    for (int ds = 0; ds < 4; ++ds)
        s0 = __builtin_amdgcn_mfma_f32_32x32x16_bf16(kf[ds], qf[ds], s0, 0, 0, 0);
#pragma unroll
    for (int ds = 0; ds < 4; ++ds)
        s1 = __builtin_amdgcn_mfma_f32_32x32x16_bf16(kf[4 + ds], qf[ds], s1, 0, 0, 0);
    __builtin_amdgcn_s_setprio(0);

    if (DIAG) {
#pragma unroll
        for (int r = 0; r < 16; ++r) {
            const int kvr = kv0 + (r & 3) + 8 * (r >> 2) + 4 * hi;
            if (kvr > qrow)      s0[r] = -3.0e38f;
            if (kvr + 32 > qrow) s1[r] = -3.0e38f;
        }
    }

    float r0 = 0.f, r1 = 0.f, r2 = 0.f, r3 = 0.f;
    unsigned w0[8], w1[8];
#pragma unroll
    for (int i = 0; i < 8; ++i) {
        const float p0 = ex2(__builtin_fmaf(s0[2 * i],     CEXP, -MCF));
        const float p1 = ex2(__builtin_fmaf(s0[2 * i + 1], CEXP, -MCF));
        const float p2 = ex2(__builtin_fmaf(s1[2 * i],     CEXP, -MCF));
        const float p3 = ex2(__builtin_fmaf(s1[2 * i + 1], CEXP, -MCF));
        r0 += p0; r1 += p1; r2 += p2; r3 += p3;
        w0[i] = pack2rb(p0, p1);
        w1[i] = pack2rb(p2, p3);
    }
    l += (r0 + r1) + (r2 + r3);

    __builtin_amdgcn_s_setprio(1);
#pragma unroll
    for (int c = 0; c < 2; ++c) {
        const unsigned* w = (c == 0) ? w0 : w1;
        unsigned a0 = w[0], a2 = w[2]; plswap(a0, a2);
        unsigned a1 = w[1], a3 = w[3]; plswap(a1, a3);
        unsigned a4 = w[4], a6 = w[6]; plswap(a4, a6);
        unsigned a5 = w[5], a7 = w[7]; plswap(a5, a7);
        u32x4 lo, hw;
        lo[0] = a0; lo[1] = a1; lo[2] = a2; lo[3] = a3;
        hw[0] = a4; hw[1] = a5; hw[2] = a6; hw[3] = a7;
        const bf16x8 paL = __builtin_bit_cast(bf16x8, lo);
        const bf16x8 paH = __builtin_bit_cast(bf16x8, hw);

        o0 = __builtin_amdgcn_mfma_f32_32x32x16_bf16(paL, vb[c * 4 + 0], o0, 0, 0, 0);
        o1 = __builtin_amdgcn_mfma_f32_32x32x16_bf16(paL, vb[c * 4 + 1], o1, 0, 0, 0);
        o0 = __builtin_amdgcn_mfma_f32_32x32x16_bf16(paH, vb[c * 4 + 2], o0, 0, 0, 0);
        o1 = __builtin_amdgcn_mfma_f32_32x32x16_bf16(paH, vb[c * 4 + 3], o1, 0, 0, 0);
    }
    __builtin_amdgcn_s_setprio(0);
}

// ---------------------------------------------------------------------------
// Causal flash attention, DBUF-pairwise pipeline (32 KB LDS -> 4 blocks/CU).
// grid 1024 (heavy-first: qt = 31 - bid/32), block 128 = 2 warps x 32 q-rows.
// Phase: read_frags(t->r0, t+1->r1); lgkmcnt+barrier; ISSUE(t+2,t+3 into the
// SAME two buffers); compute(t); compute(t+1); vmcnt(0)+barrier.
// ---------------------------------------------------------------------------
__global__ __launch_bounds__(128) void attn_kernel(
    const short* __restrict__ Q, const short* __restrict__ K,
    const short* __restrict__ VtG, short* __restrict__ O) {
    __shared__ short KbA[4096], VbA[4096], KbB[4096], VbB[4096];  // 32 KB

    const int tid = threadIdx.x, lane = tid & 63, wid = tid >> 6;
    const int l31 = lane & 31, hi = lane >> 5;
    const int bid = blockIdx.x;
    const int qt = 31 - (bid >> 5);
    const int bh = bid & 31;
    const int b = bh >> 4, h = bh & 15;
    const size_t base = (size_t)b * 2048 * 1024 + (size_t)h * 64;
    const short* Qp = Q + base;
    const short* Kp = K + base;
    const short* Vp = VtG + (size_t)(h * 64) * 4096 + (size_t)b * 2048;
    short* Op = O + base;

    const int q0w = qt * 64 + wid * 32;
    const int qrow = q0w + l31;

    const int srw = lane >> 3;
    const int swc = ((lane & 7) ^ srw) * 8;
    const short* kSrc = Kp + (size_t)srw * 1024 + swc;
    const short* vSrc = Vp + (size_t)srw * 4096 + swc;
    const int cc0 = wid * 4;

    const int nt = qt + 1;

#define ISS(i, Ksb, Vsb)                                                       \
    if ((i) < nt) {                                                            \
        const int kv0i = (i) * 64;                                             \
        _Pragma("unroll")                                                      \
        for (int c = 0; c < 4; ++c) {                                          \
            const int cc = cc0 + c;                                            \
            gload16(kSrc + (size_t)(kv0i + cc * 8) * 1024, (Ksb) + cc * 512);  \
            gload16(vSrc + (size_t)(cc * 8) * 4096 + kv0i, (Vsb) + cc * 512);  \
        }                                                                      \
    }

    // ---- prologue: stage tiles 0,1 ----
    ISS(0, KbA, VbA); ISS(1, KbB, VbB);

    bf16x8 qf[4];
#pragma unroll
    for (int ds = 0; ds < 4; ++ds)
        qf[ds] = ld8(Qp + (size_t)qrow * 1024 + ds * 16 + hi * 8);

    asm volatile("s_waitcnt vmcnt(0)" ::: "memory");
    __builtin_amdgcn_s_barrier();
    __builtin_amdgcn_sched_barrier(0);

    f32x16 o0 = 0.0f, o1 = 0.0f;
    float l = 0.0f;
    bf16x8 kf0[8], vb0[8], kf1[8], vb1[8];

    int t = 0;
#pragma unroll 1
    while (t < nt) {
        // read pair frags from LDS into regs
        read_frags(KbA, VbA, l31, hi, kf0, vb0);
        if (t + 1 < nt) read_frags(KbB, VbB, l31, hi, kf1, vb1);
        // all lanes/waves done reading -> safe to overwrite buffers
        asm volatile("s_waitcnt lgkmcnt(0)" ::: "memory");
        __builtin_amdgcn_s_barrier();
        __builtin_amdgcn_sched_barrier(0);
        ISS(t + 2, KbA, VbA);
        ISS(t + 3, KbB, VbB);
        __builtin_amdgcn_sched_barrier(0);
        // compute pair from registers (loads for t+2/t+3 in flight)
        if (t == nt - 1)
            attn_tile_r<true>(t * 64, kf0, vb0, qf, o0, o1, l, qrow, hi);
        else
            attn_tile_r<false>(t * 64, kf0, vb0, qf, o0, o1, l, qrow, hi);
        if (t + 1 < nt) {
            if (t + 1 == nt - 1)
                attn_tile_r<true>((t + 1) * 64, kf1, vb1, qf, o0, o1, l, qrow, hi);
            else
                attn_tile_r<false>((t + 1) * 64, kf1, vb1, qf, o0, o1, l, qrow, hi);
        }
        t += 2;
        if (t < nt) {
            asm volatile("s_waitcnt vmcnt(0)" ::: "memory");
            __builtin_amdgcn_s_barrier();
            __builtin_amdgcn_sched_barrier(0);
        }
    }
#undef ISS

    const float lt = l + __shfl_xor(l, 32, 64);
    const float il = 1.0f / lt;
#pragma unroll
    for (int r = 0; r < 16; ++r) {
        const int cr = (r & 3) + 8 * (r >> 2) + 4 * hi;
        const float s = __shfl(il, cr, 64);
        const size_t row = (size_t)(q0w + cr) * 1024;
        Op[row + l31]      = f2bfs(o0[r] * s);
        Op[row + 32 + l31] = f2bfs(o1[r] * s);
    }
}

// ---------------------------------------------------------------------------
extern "C" void kernel_launch(void* const* d_in, const int* in_sizes, int n_in,
                              void* d_out, int out_size, void* d_ws, size_t ws_size,
                              hipStream_t stream) {
    const float* x  = (const float*)d_in[0];
    const float* Wq = (const float*)d_in[1];
    const float* Wk = (const float*)d_in[2];
    const float* Wv = (const float*)d_in[3];
    const float* Wo = (const float*)d_in[4];

    short* wb  = (short*)d_ws;                 // 4 x 1M shorts (8 MB)
    short* Qw  = wb + (size_t)4 * 1048576;     // 8 MB (attn out aliases this)
    short* Kw  = Qw + (size_t)4194304;         // 8 MB
    short* Vtw = Kw + (size_t)4194304;         // 8 MB  (VtG[1024][4096])
    short* xb  = (short*)d_out;                // bf16 x lives in d_out[0:8MB]

    convert_kernel<<<4096, 256, 0, stream>>>(x, Wq, Wk, Wv, Wo, xb, wb);
    gemm_qkv_kernel<<<768, 256, 0, stream>>>(xb, wb, Qw, Kw, Vtw);
    attn_kernel<<<1024, 128, 0, stream>>>(Qw, Kw, Vtw, Qw);
    gemm_wo_kernel<<<dim3(64, 8), 256, 0, stream>>>(Qw, wb + (size_t)3 * 1048576, (float*)d_out);
}

// Round 20
// 107.306 us; speedup vs baseline: 1.0643x; 1.0643x over previous
//
#include <hip/hip_runtime.h>
#include <hip/hip_bf16.h>

// ---------------------------------------------------------------------------
// MHSA: x[2,2048,1024] f32, Wq/Wk/Wv/Wo[1024,1024] f32 -> out[2,2048,1024] f32.
// Internal bf16. Pipeline (R19 attn + R16 QKV grid):
//   1) convert: x -> xb (bf16 in d_out[0:8MB]); W* -> wb (ws)
//   2) fused QKV GEMM: BK=64 single-buffer, XOR-swizzled gload staging,
//      2-D grid (32,24) natural mapping (R16 — XCD experiments closed).
//   3) causal flash attention: dbuf-pairwise (R19): 2 waves / 64 q-rows,
//      pairwise compute from reg-held frags, 32 KB LDS (4 blocks/CU),
//      fixed-shift softmax, permlane32_swap, perm-pack.
//   4) Wo GEMM (R16): 64x128 tiles (512 blocks = 2/CU).
// ws (shorts): wb[4x1M] Q[4M] K[4M] VtG[4M] = 32 MB. attn out aliases Q.
// ---------------------------------------------------------------------------

#define DEVI __device__ __forceinline__

typedef __bf16 bf16x8 __attribute__((ext_vector_type(8)));
typedef short  short8 __attribute__((ext_vector_type(8)));
typedef float  f32x4  __attribute__((ext_vector_type(4)));
typedef float  f32x16 __attribute__((ext_vector_type(16)));
typedef unsigned int u32x4 __attribute__((ext_vector_type(4)));

DEVI short f2bfs(float f) {
    __hip_bfloat16 h = __float2bfloat16(f);
    return __builtin_bit_cast(short, h);
}
DEVI unsigned pack2rb(float a, float b) {
    const unsigned ua = __builtin_bit_cast(unsigned, a) + 0x8000u;
    const unsigned ub = __builtin_bit_cast(unsigned, b) + 0x8000u;
    return __builtin_amdgcn_perm(ub, ua, 0x07060302u);
}
DEVI bf16x8 ld8(const short* p) {
    return __builtin_bit_cast(bf16x8, *(const short8*)p);
}
DEVI void gload16(const void* g, void* lds) {
    __builtin_amdgcn_global_load_lds(
        (const __attribute__((address_space(1))) void*)g,
        (__attribute__((address_space(3))) void*)lds, 16, 0, 0);
}
DEVI void plswap(unsigned& a, unsigned& b) {
    asm volatile("v_permlane32_swap_b32 %0, %1" : "+v"(a), "+v"(b));
}
// XOR-swizzled LDS read address for [R][64] bf16 tiles: byte ^= (row&7)<<4.
DEVI const short* lds_swc(const short* base, int row, int col) {
    return (const short*)((const char*)base + (((row << 7) + (col << 1)) ^ ((row & 7) << 4)));
}

#if defined(__has_builtin)
#if __has_builtin(__builtin_amdgcn_exp2f)
#define HAVE_EXP2 1
#endif
#endif
DEVI float ex2(float x) {
#ifdef HAVE_EXP2
    return __builtin_amdgcn_exp2f(x);
#else
    return __expf(x * 0.69314718055994531f);
#endif
}
#define CEXP 0.18033688011112042f
#define MCF  (64.0f * CEXP)   // fixed softmax shift (raw-score domain)

// ---------------------------------------------------------------------------
// f32 -> bf16 convert, 1-D exact grid.
// ---------------------------------------------------------------------------
__global__ __launch_bounds__(256) void convert_kernel(
    const float* __restrict__ x, const float* __restrict__ Wq,
    const float* __restrict__ Wk, const float* __restrict__ Wv,
    const float* __restrict__ Wo, short* __restrict__ xb, short* __restrict__ wb) {
    const int bid = blockIdx.x;
    const float* src;
    short* dst;
    int i8;
    if (bid < 2048) {
        src = x; dst = xb;
        i8 = (bid * 256 + threadIdx.x) * 8;
    } else {
        const int w = bid - 2048;
        const int z = w >> 9;
        src = (z == 0) ? Wq : (z == 1) ? Wk : (z == 2) ? Wv : Wo;
        dst = wb + (size_t)z * 1048576;
        i8 = (((w & 511) * 256) + threadIdx.x) * 8;
    }
    float4 a = ((const float4*)(src + i8))[0];
    float4 b = ((const float4*)(src + i8))[1];
    short8 t;
    t[0] = f2bfs(a.x); t[1] = f2bfs(a.y); t[2] = f2bfs(a.z); t[3] = f2bfs(a.w);
    t[4] = f2bfs(b.x); t[5] = f2bfs(b.y); t[6] = f2bfs(b.z); t[7] = f2bfs(b.w);
    *(short8*)(dst + i8) = t;
}

// ---------------------------------------------------------------------------
// bf16 NT-GEMM K-loop (R16): BK=64, single-buffer, XOR-swizzled staging.
// ---------------------------------------------------------------------------
template <int BM, int BN, int MF, int NF, int WN>
DEVI void gemm_kloop64(const short* __restrict__ A, const short* __restrict__ B,
                       short* As, short* Bs, int wid, int lane, f32x4 acc[MF][NF]) {
    const int l15 = lane & 15, l4 = lane >> 4;
    const int wm = wid / WN, wn = wid % WN;
    const int rowc = lane >> 3;
    const int gcol = ((lane & 7) ^ rowc) * 8;
    constexpr int NCHA = BM / 8, NCHB = BN / 8;
#pragma unroll 1
    for (int k0 = 0; k0 < 1024; k0 += 64) {
        __syncthreads();
#pragma unroll
        for (int c = wid; c < NCHA; c += 4)
            gload16(A + (size_t)(c * 8 + rowc) * 1024 + k0 + gcol, As + c * 512);
#pragma unroll
        for (int c = wid; c < NCHB; c += 4)
            gload16(B + (size_t)(c * 8 + rowc) * 1024 + k0 + gcol, Bs + c * 512);
        __syncthreads();
#pragma unroll
        for (int kk = 0; kk < 2; ++kk) {
            bf16x8 af[MF], bf[NF];
#pragma unroll
            for (int m = 0; m < MF; ++m) {
                const int row = wm * (MF * 16) + m * 16 + l15;
                af[m] = ld8(As + row * 64 + (((kk * 4 + l4) ^ (row & 7)) * 8));
            }
#pragma unroll
            for (int n = 0; n < NF; ++n) {
                const int row = wn * (NF * 16) + n * 16 + l15;
                bf[n] = ld8(Bs + row * 64 + (((kk * 4 + l4) ^ (row & 7)) * 8));
            }
#pragma unroll
            for (int m = 0; m < MF; ++m)
#pragma unroll
                for (int n = 0; n < NF; ++n)
                    acc[m][n] = __builtin_amdgcn_mfma_f32_16x16x32_bf16(af[m], bf[n], acc[m][n], 0, 0, 0);
        }
    }
}

// ---------------------------------------------------------------------------
// Fused QKV projection (R16). grid (32, 24): y>>3 weight; (y&7) col tile.
// ---------------------------------------------------------------------------
__global__ __launch_bounds__(256) void gemm_qkv_kernel(
    const short* __restrict__ xb, const short* __restrict__ wb,
    short* __restrict__ Qo, short* __restrict__ Ko, short* __restrict__ VtG) {
    __shared__ short As[8192], Bs[8192];
    const int tid = threadIdx.x, lane = tid & 63, wid = tid >> 6;
    const int l15 = lane & 15, l4 = lane >> 4;
    const int wm = wid >> 1, wn = wid & 1;
    const int y = blockIdx.y, wsel = y >> 3;
    const int row0 = blockIdx.x * 128, col0 = (y & 7) * 128;

    f32x4 acc[4][4] = {};
    gemm_kloop64<128, 128, 4, 4, 2>(
        xb + (size_t)row0 * 1024,
        wb + (size_t)wsel * 1048576 + (size_t)col0 * 1024,
        As, Bs, wid, lane, acc);

    if (wsel == 2) {
#pragma unroll
        for (int m = 0; m < 4; ++m)
#pragma unroll
            for (int n = 0; n < 4; ++n)
#pragma unroll
                for (int j = 0; j < 4; ++j) {
                    int row = row0 + wm * 64 + m * 16 + l4 * 4 + j;
                    int col = col0 + wn * 64 + n * 16 + l15;
                    VtG[(size_t)col * 4096 + row] = f2bfs(acc[m][n][j]);
                }
    } else {
        short* C = (wsel == 0) ? Qo : Ko;
#pragma unroll
        for (int m = 0; m < 4; ++m)
#pragma unroll
            for (int n = 0; n < 4; ++n)
#pragma unroll
                for (int j = 0; j < 4; ++j) {
                    int row = row0 + wm * 64 + m * 16 + l4 * 4 + j;
                    int col = col0 + wn * 64 + n * 16 + l15;
                    C[(size_t)row * 1024 + col] = f2bfs(acc[m][n][j]);
                }
    }
}

// ---------------------------------------------------------------------------
// Output projection (R16): 64x128 tiles (512 blocks = 2/CU), BK=64.
// ---------------------------------------------------------------------------
__global__ __launch_bounds__(256) void gemm_wo_kernel(
    const short* __restrict__ Ao, const short* __restrict__ Wob,
    float* __restrict__ Cout) {
    __shared__ short As[4096], Bs[8192];
    const int tid = threadIdx.x, lane = tid & 63, wid = tid >> 6;
    const int l15 = lane & 15, l4 = lane >> 4;
    const int wn = wid;
    const int row0 = blockIdx.x * 64, col0 = blockIdx.y * 128;

    f32x4 acc[4][2] = {};
    gemm_kloop64<64, 128, 4, 2, 4>(
        Ao + (size_t)row0 * 1024, Wob + (size_t)col0 * 1024,
        As, Bs, wid, lane, acc);

#pragma unroll
    for (int m = 0; m < 4; ++m)
#pragma unroll
        for (int n = 0; n < 2; ++n)
#pragma unroll
            for (int j = 0; j < 4; ++j) {
                const int row = row0 + m * 16 + l4 * 4 + j;
                const int col = col0 + wn * 32 + n * 16 + l15;
                Cout[(size_t)row * 1024 + col] = acc[m][n][j];
            }
}

// ---------------------------------------------------------------------------
// Read the 16 MFMA fragments of one KV tile from (swizzled) LDS into regs.
// ---------------------------------------------------------------------------
DEVI void read_frags(const short* Ks, const short* Vts, int l31, int hi,
                     bf16x8 kf[8], bf16x8 vb[8]) {
#pragma unroll
    for (int ds = 0; ds < 4; ++ds) {
        kf[ds]     = ld8(lds_swc(Ks, l31,      ds * 16 + hi * 8));
        kf[4 + ds] = ld8(lds_swc(Ks, 32 + l31, ds * 16 + hi * 8));
    }
#pragma unroll
    for (int c = 0; c < 2; ++c) {
        vb[c * 4 + 0] = ld8(lds_swc(Vts, l31,      c * 32 + hi * 8));
        vb[c * 4 + 1] = ld8(lds_swc(Vts, 32 + l31, c * 32 + hi * 8));
        vb[c * 4 + 2] = ld8(lds_swc(Vts, l31,      c * 32 + 16 + hi * 8));
        vb[c * 4 + 3] = ld8(lds_swc(Vts, 32 + l31, c * 32 + 16 + hi * 8));
    }
}

// ---------------------------------------------------------------------------
// One KV tile from register frags, fixed-shift softmax (R16, verified).
// ---------------------------------------------------------------------------
template <bool DIAG>
DEVI void attn_tile_r(int kv0, const bf16x8 kf[8], const bf16x8 vb[8],
                      const bf16x8 qf[4], f32x16& o0, f32x16& o1,
                      float& l, int qrow, int hi) {
    f32x16 s0 = 0.0f, s1 = 0.0f;
    __builtin_amdgcn_s_setprio(1);
#pragma unroll
    for (int ds = 0; ds < 4; ++ds)
        s0 = __builtin_amdgcn_mfma_f32_32x32x16_bf16(kf[ds], qf[ds], s0, 0, 0, 0);
#pragma unroll
    for (int ds = 0; ds < 4; ++ds)
        s1 = __builtin_amdgcn_mfma_f32_32x32x16_bf16(kf[4 + ds], qf[ds], s1, 0, 0, 0);
    __builtin_amdgcn_s_setprio(0);

    if (DIAG) {
#pragma unroll
        for (int r = 0; r < 16; ++r) {
            const int kvr = kv0 + (r & 3) + 8 * (r >> 2) + 4 * hi;
            if (kvr > qrow)      s0[r] = -3.0e38f;
            if (kvr + 32 > qrow) s1[r] = -3.0e38f;
        }
    }

    float r0 = 0.f, r1 = 0.f, r2 = 0.f, r3 = 0.f;
    unsigned w0[8], w1[8];
#pragma unroll
    for (int i = 0; i < 8; ++i) {
        const float p0 = ex2(__builtin_fmaf(s0[2 * i],     CEXP, -MCF));
        const float p1 = ex2(__builtin_fmaf(s0[2 * i + 1], CEXP, -MCF));
        const float p2 = ex2(__builtin_fmaf(s1[2 * i],     CEXP, -MCF));
        const float p3 = ex2(__builtin_fmaf(s1[2 * i + 1], CEXP, -MCF));
        r0 += p0; r1 += p1; r2 += p2; r3 += p3;
        w0[i] = pack2rb(p0, p1);
        w1[i] = pack2rb(p2, p3);
    }
    l += (r0 + r1) + (r2 + r3);

    __builtin_amdgcn_s_setprio(1);
#pragma unroll
    for (int c = 0; c < 2; ++c) {
        const unsigned* w = (c == 0) ? w0 : w1;
        unsigned a0 = w[0], a2 = w[2]; plswap(a0, a2);
        unsigned a1 = w[1], a3 = w[3]; plswap(a1, a3);
        unsigned a4 = w[4], a6 = w[6]; plswap(a4, a6);
        unsigned a5 = w[5], a7 = w[7]; plswap(a5, a7);
        u32x4 lo, hw;
        lo[0] = a0; lo[1] = a1; lo[2] = a2; lo[3] = a3;
        hw[0] = a4; hw[1] = a5; hw[2] = a6; hw[3] = a7;
        const bf16x8 paL = __builtin_bit_cast(bf16x8, lo);
        const bf16x8 paH = __builtin_bit_cast(bf16x8, hw);

        o0 = __builtin_amdgcn_mfma_f32_32x32x16_bf16(paL, vb[c * 4 + 0], o0, 0, 0, 0);
        o1 = __builtin_amdgcn_mfma_f32_32x32x16_bf16(paL, vb[c * 4 + 1], o1, 0, 0, 0);
        o0 = __builtin_amdgcn_mfma_f32_32x32x16_bf16(paH, vb[c * 4 + 2], o0, 0, 0, 0);
        o1 = __builtin_amdgcn_mfma_f32_32x32x16_bf16(paH, vb[c * 4 + 3], o1, 0, 0, 0);
    }
    __builtin_amdgcn_s_setprio(0);
}

// ---------------------------------------------------------------------------
// Causal flash attention, DBUF-pairwise pipeline (32 KB LDS -> 4 blocks/CU).
// grid 1024 (heavy-first: qt = 31 - bid/32), block 128 = 2 warps x 32 q-rows.
// Phase: read_frags(t->r0, t+1->r1); lgkmcnt+barrier; ISSUE(t+2,t+3 into the
// SAME two buffers); compute(t); compute(t+1); vmcnt(0)+barrier.
// ---------------------------------------------------------------------------
__global__ __launch_bounds__(128) void attn_kernel(
    const short* __restrict__ Q, const short* __restrict__ K,
    const short* __restrict__ VtG, short* __restrict__ O) {
    __shared__ short KbA[4096], VbA[4096], KbB[4096], VbB[4096];  // 32 KB

    const int tid = threadIdx.x, lane = tid & 63, wid = tid >> 6;
    const int l31 = lane & 31, hi = lane >> 5;
    const int bid = blockIdx.x;
    const int qt = 31 - (bid >> 5);
    const int bh = bid & 31;
    const int b = bh >> 4, h = bh & 15;
    const size_t base = (size_t)b * 2048 * 1024 + (size_t)h * 64;
    const short* Qp = Q + base;
    const short* Kp = K + base;
    const short* Vp = VtG + (size_t)(h * 64) * 4096 + (size_t)b * 2048;
    short* Op = O + base;

    const int q0w = qt * 64 + wid * 32;
    const int qrow = q0w + l31;

    const int srw = lane >> 3;
    const int swc = ((lane & 7) ^ srw) * 8;
    const short* kSrc = Kp + (size_t)srw * 1024 + swc;
    const short* vSrc = Vp + (size_t)srw * 4096 + swc;
    const int cc0 = wid * 4;

    const int nt = qt + 1;

#define ISS(i, Ksb, Vsb)                                                       \
    if ((i) < nt) {                                                            \
        const int kv0i = (i) * 64;                                             \
        _Pragma("unroll")                                                      \
        for (int c = 0; c < 4; ++c) {                                          \
            const int cc = cc0 + c;                                            \
            gload16(kSrc + (size_t)(kv0i + cc * 8) * 1024, (Ksb) + cc * 512);  \
            gload16(vSrc + (size_t)(cc * 8) * 4096 + kv0i, (Vsb) + cc * 512);  \
        }                                                                      \
    }

    // ---- prologue: stage tiles 0,1 ----
    ISS(0, KbA, VbA); ISS(1, KbB, VbB);

    bf16x8 qf[4];
#pragma unroll
    for (int ds = 0; ds < 4; ++ds)
        qf[ds] = ld8(Qp + (size_t)qrow * 1024 + ds * 16 + hi * 8);

    asm volatile("s_waitcnt vmcnt(0)" ::: "memory");
    __builtin_amdgcn_s_barrier();
    __builtin_amdgcn_sched_barrier(0);

    f32x16 o0 = 0.0f, o1 = 0.0f;
    float l = 0.0f;
    bf16x8 kf0[8], vb0[8], kf1[8], vb1[8];

    int t = 0;
#pragma unroll 1
    while (t < nt) {
        // read pair frags from LDS into regs
        read_frags(KbA, VbA, l31, hi, kf0, vb0);
        if (t + 1 < nt) read_frags(KbB, VbB, l31, hi, kf1, vb1);
        // all lanes/waves done reading -> safe to overwrite buffers
        asm volatile("s_waitcnt lgkmcnt(0)" ::: "memory");
        __builtin_amdgcn_s_barrier();
        __builtin_amdgcn_sched_barrier(0);
        ISS(t + 2, KbA, VbA);
        ISS(t + 3, KbB, VbB);
        __builtin_amdgcn_sched_barrier(0);
        // compute pair from registers (loads for t+2/t+3 in flight)
        if (t == nt - 1)
            attn_tile_r<true>(t * 64, kf0, vb0, qf, o0, o1, l, qrow, hi);
        else
            attn_tile_r<false>(t * 64, kf0, vb0, qf, o0, o1, l, qrow, hi);
        if (t + 1 < nt) {
            if (t + 1 == nt - 1)
                attn_tile_r<true>((t + 1) * 64, kf1, vb1, qf, o0, o1, l, qrow, hi);
            else
                attn_tile_r<false>((t + 1) * 64, kf1, vb1, qf, o0, o1, l, qrow, hi);
        }
        t += 2;
        if (t < nt) {
            asm volatile("s_waitcnt vmcnt(0)" ::: "memory");
            __builtin_amdgcn_s_barrier();
            __builtin_amdgcn_sched_barrier(0);
        }
    }
#undef ISS

    const float lt = l + __shfl_xor(l, 32, 64);
    const float il = 1.0f / lt;
#pragma unroll
    for (int r = 0; r < 16; ++r) {
        const int cr = (r & 3) + 8 * (r >> 2) + 4 * hi;
        const float s = __shfl(il, cr, 64);
        const size_t row = (size_t)(q0w + cr) * 1024;
        Op[row + l31]      = f2bfs(o0[r] * s);
        Op[row + 32 + l31] = f2bfs(o1[r] * s);
    }
}

// ---------------------------------------------------------------------------
extern "C" void kernel_launch(void* const* d_in, const int* in_sizes, int n_in,
                              void* d_out, int out_size, void* d_ws, size_t ws_size,
                              hipStream_t stream) {
    const float* x  = (const float*)d_in[0];
    const float* Wq = (const float*)d_in[1];
    const float* Wk = (const float*)d_in[2];
    const float* Wv = (const float*)d_in[3];
    const float* Wo = (const float*)d_in[4];

    short* wb  = (short*)d_ws;                 // 4 x 1M shorts (8 MB)
    short* Qw  = wb + (size_t)4 * 1048576;     // 8 MB (attn out aliases this)
    short* Kw  = Qw + (size_t)4194304;         // 8 MB
    short* Vtw = Kw + (size_t)4194304;         // 8 MB  (VtG[1024][4096])
    short* xb  = (short*)d_out;                // bf16 x lives in d_out[0:8MB]

    convert_kernel<<<4096, 256, 0, stream>>>(x, Wq, Wk, Wv, Wo, xb, wb);
    gemm_qkv_kernel<<<dim3(32, 24), 256, 0, stream>>>(xb, wb, Qw, Kw, Vtw);
    attn_kernel<<<1024, 128, 0, stream>>>(Qw, Kw, Vtw, Qw);
    gemm_wo_kernel<<<dim3(64, 8), 256, 0, stream>>>(Qw, wb + (size_t)3 * 1048576, (float*)d_out);
}

// Round 21
// 101.087 us; speedup vs baseline: 1.1298x; 1.0615x over previous
//
#include <hip/hip_runtime.h>
#include <hip/hip_bf16.h>

// ---------------------------------------------------------------------------
// MHSA: x[2,2048,1024] f32, Wq/Wk/Wv/Wo[1024,1024] f32 -> out[2,2048,1024] f32.
// Internal bf16. Pipeline (R20 + pairwise reg-frag GEMM kloop):
//   1) convert: x -> xb (bf16 in d_out[0:8MB]); W* -> wb (ws)
//   2) fused QKV GEMM: BK=64, 32KB single LDS buffer, per K-step:
//      read frags->regs, barrier, ISSUE(k+1) same bufs, MFMA from regs,
//      vmcnt(0)+barrier (R19-attn pattern: drain covered by compute).
//   3) causal flash attention (R19/R20): dbuf-pairwise, reg-frags,
//      fixed-shift softmax, permlane32_swap, perm-pack.
//   4) Wo GEMM: same reg-frag kloop, 64x128 tiles (512 blocks = 2/CU).
// ws (shorts): wb[4x1M] Q[4M] K[4M] VtG[4M] = 32 MB. attn out aliases Q.
// ---------------------------------------------------------------------------

#define DEVI __device__ __forceinline__

typedef __bf16 bf16x8 __attribute__((ext_vector_type(8)));
typedef short  short8 __attribute__((ext_vector_type(8)));
typedef float  f32x4  __attribute__((ext_vector_type(4)));
typedef float  f32x16 __attribute__((ext_vector_type(16)));
typedef unsigned int u32x4 __attribute__((ext_vector_type(4)));

DEVI short f2bfs(float f) {
    __hip_bfloat16 h = __float2bfloat16(f);
    return __builtin_bit_cast(short, h);
}
DEVI unsigned pack2rb(float a, float b) {
    const unsigned ua = __builtin_bit_cast(unsigned, a) + 0x8000u;
    const unsigned ub = __builtin_bit_cast(unsigned, b) + 0x8000u;
    return __builtin_amdgcn_perm(ub, ua, 0x07060302u);
}
DEVI bf16x8 ld8(const short* p) {
    return __builtin_bit_cast(bf16x8, *(const short8*)p);
}
DEVI void gload16(const void* g, void* lds) {
    __builtin_amdgcn_global_load_lds(
        (const __attribute__((address_space(1))) void*)g,
        (__attribute__((address_space(3))) void*)lds, 16, 0, 0);
}
DEVI void plswap(unsigned& a, unsigned& b) {
    asm volatile("v_permlane32_swap_b32 %0, %1" : "+v"(a), "+v"(b));
}
// XOR-swizzled LDS read address for [R][64] bf16 tiles: byte ^= (row&7)<<4.
DEVI const short* lds_swc(const short* base, int row, int col) {
    return (const short*)((const char*)base + (((row << 7) + (col << 1)) ^ ((row & 7) << 4)));
}

#if defined(__has_builtin)
#if __has_builtin(__builtin_amdgcn_exp2f)
#define HAVE_EXP2 1
#endif
#endif
DEVI float ex2(float x) {
#ifdef HAVE_EXP2
    return __builtin_amdgcn_exp2f(x);
#else
    return __expf(x * 0.69314718055994531f);
#endif
}
#define CEXP 0.18033688011112042f
#define MCF  (64.0f * CEXP)   // fixed softmax shift (raw-score domain)

// ---------------------------------------------------------------------------
// f32 -> bf16 convert, 1-D exact grid.
// ---------------------------------------------------------------------------
__global__ __launch_bounds__(256) void convert_kernel(
    const float* __restrict__ x, const float* __restrict__ Wq,
    const float* __restrict__ Wk, const float* __restrict__ Wv,
    const float* __restrict__ Wo, short* __restrict__ xb, short* __restrict__ wb) {
    const int bid = blockIdx.x;
    const float* src;
    short* dst;
    int i8;
    if (bid < 2048) {
        src = x; dst = xb;
        i8 = (bid * 256 + threadIdx.x) * 8;
    } else {
        const int w = bid - 2048;
        const int z = w >> 9;
        src = (z == 0) ? Wq : (z == 1) ? Wk : (z == 2) ? Wv : Wo;
        dst = wb + (size_t)z * 1048576;
        i8 = (((w & 511) * 256) + threadIdx.x) * 8;
    }
    float4 a = ((const float4*)(src + i8))[0];
    float4 b = ((const float4*)(src + i8))[1];
    short8 t;
    t[0] = f2bfs(a.x); t[1] = f2bfs(a.y); t[2] = f2bfs(a.z); t[3] = f2bfs(a.w);
    t[4] = f2bfs(b.x); t[5] = f2bfs(b.y); t[6] = f2bfs(b.z); t[7] = f2bfs(b.w);
    *(short8*)(dst + i8) = t;
}

// ---------------------------------------------------------------------------
// bf16 NT-GEMM K-loop, BK=64, single 32KB LDS buffer, R19-attn phase pattern:
//   read frags(k)->regs; lgkmcnt+barrier; ISSUE(k+1) same bufs;
//   32 MFMA from regs; vmcnt(0)+barrier.
// ---------------------------------------------------------------------------
template <int BM, int BN, int MF, int NF, int WN>
DEVI void gemm_kloop64(const short* __restrict__ A, const short* __restrict__ B,
                       short* As, short* Bs, int wid, int lane, f32x4 acc[MF][NF]) {
    const int l15 = lane & 15, l4 = lane >> 4;
    const int wm = wid / WN, wn = wid % WN;
    const int rowc = lane >> 3;
    const int gcol = ((lane & 7) ^ rowc) * 8;
    constexpr int NCHA = BM / 8, NCHB = BN / 8;

#define GISSUE(k0_)                                                            \
    {                                                                          \
        _Pragma("unroll")                                                      \
        for (int c = wid; c < NCHA; c += 4)                                    \
            gload16(A + (size_t)(c * 8 + rowc) * 1024 + (k0_) + gcol, As + c * 512); \
        _Pragma("unroll")                                                      \
        for (int c = wid; c < NCHB; c += 4)                                    \
            gload16(B + (size_t)(c * 8 + rowc) * 1024 + (k0_) + gcol, Bs + c * 512); \
    }

    GISSUE(0);
    asm volatile("s_waitcnt vmcnt(0)" ::: "memory");
    __builtin_amdgcn_s_barrier();
    __builtin_amdgcn_sched_barrier(0);

#pragma unroll 1
    for (int k = 0; k < 16; ++k) {
        bf16x8 af[2][MF], bf[2][NF];
#pragma unroll
        for (int kk = 0; kk < 2; ++kk) {
#pragma unroll
            for (int m = 0; m < MF; ++m) {
                const int row = wm * (MF * 16) + m * 16 + l15;
                af[kk][m] = ld8(As + row * 64 + (((kk * 4 + l4) ^ (row & 7)) * 8));
            }
#pragma unroll
            for (int n = 0; n < NF; ++n) {
                const int row = wn * (NF * 16) + n * 16 + l15;
                bf[kk][n] = ld8(Bs + row * 64 + (((kk * 4 + l4) ^ (row & 7)) * 8));
            }
        }
        // all waves done reading LDS -> safe to overwrite with next K-step
        asm volatile("s_waitcnt lgkmcnt(0)" ::: "memory");
        __builtin_amdgcn_s_barrier();
        __builtin_amdgcn_sched_barrier(0);
        if (k + 1 < 16) GISSUE((k + 1) * 64);
        __builtin_amdgcn_sched_barrier(0);
        // compute from registers; staged loads in flight underneath
        __builtin_amdgcn_s_setprio(1);
#pragma unroll
        for (int kk = 0; kk < 2; ++kk)
#pragma unroll
            for (int m = 0; m < MF; ++m)
#pragma unroll
                for (int n = 0; n < NF; ++n)
                    acc[m][n] = __builtin_amdgcn_mfma_f32_16x16x32_bf16(af[kk][m], bf[kk][n], acc[m][n], 0, 0, 0);
        __builtin_amdgcn_s_setprio(0);
        if (k + 1 < 16) {
            asm volatile("s_waitcnt vmcnt(0)" ::: "memory");
            __builtin_amdgcn_s_barrier();
            __builtin_amdgcn_sched_barrier(0);
        }
    }
#undef GISSUE
}

// ---------------------------------------------------------------------------
// Fused QKV projection. grid (32, 24): y>>3 weight; (y&7) col tile.
// ---------------------------------------------------------------------------
__global__ __launch_bounds__(256) void gemm_qkv_kernel(
    const short* __restrict__ xb, const short* __restrict__ wb,
    short* __restrict__ Qo, short* __restrict__ Ko, short* __restrict__ VtG) {
    __shared__ short As[8192], Bs[8192];
    const int tid = threadIdx.x, lane = tid & 63, wid = tid >> 6;
    const int l15 = lane & 15, l4 = lane >> 4;
    const int wm = wid >> 1, wn = wid & 1;
    const int y = blockIdx.y, wsel = y >> 3;
    const int row0 = blockIdx.x * 128, col0 = (y & 7) * 128;

    f32x4 acc[4][4] = {};
    gemm_kloop64<128, 128, 4, 4, 2>(
        xb + (size_t)row0 * 1024,
        wb + (size_t)wsel * 1048576 + (size_t)col0 * 1024,
        As, Bs, wid, lane, acc);

    if (wsel == 2) {
#pragma unroll
        for (int m = 0; m < 4; ++m)
#pragma unroll
            for (int n = 0; n < 4; ++n)
#pragma unroll
                for (int j = 0; j < 4; ++j) {
                    int row = row0 + wm * 64 + m * 16 + l4 * 4 + j;
                    int col = col0 + wn * 64 + n * 16 + l15;
                    VtG[(size_t)col * 4096 + row] = f2bfs(acc[m][n][j]);
                }
    } else {
        short* C = (wsel == 0) ? Qo : Ko;
#pragma unroll
        for (int m = 0; m < 4; ++m)
#pragma unroll
            for (int n = 0; n < 4; ++n)
#pragma unroll
                for (int j = 0; j < 4; ++j) {
                    int row = row0 + wm * 64 + m * 16 + l4 * 4 + j;
                    int col = col0 + wn * 64 + n * 16 + l15;
                    C[(size_t)row * 1024 + col] = f2bfs(acc[m][n][j]);
                }
    }
}

// ---------------------------------------------------------------------------
// Output projection: 64x128 tiles (512 blocks = 2/CU), BK=64.
// ---------------------------------------------------------------------------
__global__ __launch_bounds__(256) void gemm_wo_kernel(
    const short* __restrict__ Ao, const short* __restrict__ Wob,
    float* __restrict__ Cout) {
    __shared__ short As[4096], Bs[8192];
    const int tid = threadIdx.x, lane = tid & 63, wid = tid >> 6;
    const int l15 = lane & 15, l4 = lane >> 4;
    const int wn = wid;
    const int row0 = blockIdx.x * 64, col0 = blockIdx.y * 128;

    f32x4 acc[4][2] = {};
    gemm_kloop64<64, 128, 4, 2, 4>(
        Ao + (size_t)row0 * 1024, Wob + (size_t)col0 * 1024,
        As, Bs, wid, lane, acc);

#pragma unroll
    for (int m = 0; m < 4; ++m)
#pragma unroll
        for (int n = 0; n < 2; ++n)
#pragma unroll
            for (int j = 0; j < 4; ++j) {
                const int row = row0 + m * 16 + l4 * 4 + j;
                const int col = col0 + wn * 32 + n * 16 + l15;
                Cout[(size_t)row * 1024 + col] = acc[m][n][j];
            }
}

// ---------------------------------------------------------------------------
// Read the 16 MFMA fragments of one KV tile from (swizzled) LDS into regs.
// ---------------------------------------------------------------------------
DEVI void read_frags(const short* Ks, const short* Vts, int l31, int hi,
                     bf16x8 kf[8], bf16x8 vb[8]) {
#pragma unroll
    for (int ds = 0; ds < 4; ++ds) {
        kf[ds]     = ld8(lds_swc(Ks, l31,      ds * 16 + hi * 8));
        kf[4 + ds] = ld8(lds_swc(Ks, 32 + l31, ds * 16 + hi * 8));
    }
#pragma unroll
    for (int c = 0; c < 2; ++c) {
        vb[c * 4 + 0] = ld8(lds_swc(Vts, l31,      c * 32 + hi * 8));
        vb[c * 4 + 1] = ld8(lds_swc(Vts, 32 + l31, c * 32 + hi * 8));
        vb[c * 4 + 2] = ld8(lds_swc(Vts, l31,      c * 32 + 16 + hi * 8));
        vb[c * 4 + 3] = ld8(lds_swc(Vts, 32 + l31, c * 32 + 16 + hi * 8));
    }
}

// ---------------------------------------------------------------------------
// One KV tile from register frags, fixed-shift softmax (R16, verified).
// ---------------------------------------------------------------------------
template <bool DIAG>
DEVI void attn_tile_r(int kv0, const bf16x8 kf[8], const bf16x8 vb[8],
                      const bf16x8 qf[4], f32x16& o0, f32x16& o1,
                      float& l, int qrow, int hi) {
    f32x16 s0 = 0.0f, s1 = 0.0f;
    __builtin_amdgcn_s_setprio(1);
#pragma unroll
    for (int ds = 0; ds < 4; ++ds)
        s0 = __builtin_amdgcn_mfma_f32_32x32x16_bf16(kf[ds], qf[ds], s0, 0, 0, 0);
#pragma unroll
    for (int ds = 0; ds < 4; ++ds)
        s1 = __builtin_amdgcn_mfma_f32_32x32x16_bf16(kf[4 + ds], qf[ds], s1, 0, 0, 0);
    __builtin_amdgcn_s_setprio(0);

    if (DIAG) {
#pragma unroll
        for (int r = 0; r < 16; ++r) {
            const int kvr = kv0 + (r & 3) + 8 * (r >> 2) + 4 * hi;
            if (kvr > qrow)      s0[r] = -3.0e38f;
            if (kvr + 32 > qrow) s1[r] = -3.0e38f;
        }
    }

    float r0 = 0.f, r1 = 0.f, r2 = 0.f, r3 = 0.f;
    unsigned w0[8], w1[8];
#pragma unroll
    for (int i = 0; i < 8; ++i) {
        const float p0 = ex2(__builtin_fmaf(s0[2 * i],     CEXP, -MCF));
        const float p1 = ex2(__builtin_fmaf(s0[2 * i + 1], CEXP, -MCF));
        const float p2 = ex2(__builtin_fmaf(s1[2 * i],     CEXP, -MCF));
        const float p3 = ex2(__builtin_fmaf(s1[2 * i + 1], CEXP, -MCF));
        r0 += p0; r1 += p1; r2 += p2; r3 += p3;
        w0[i] = pack2rb(p0, p1);
        w1[i] = pack2rb(p2, p3);
    }
    l += (r0 + r1) + (r2 + r3);

    __builtin_amdgcn_s_setprio(1);
#pragma unroll
    for (int c = 0; c < 2; ++c) {
        const unsigned* w = (c == 0) ? w0 : w1;
        unsigned a0 = w[0], a2 = w[2]; plswap(a0, a2);
        unsigned a1 = w[1], a3 = w[3]; plswap(a1, a3);
        unsigned a4 = w[4], a6 = w[6]; plswap(a4, a6);
        unsigned a5 = w[5], a7 = w[7]; plswap(a5, a7);
        u32x4 lo, hw;
        lo[0] = a0; lo[1] = a1; lo[2] = a2; lo[3] = a3;
        hw[0] = a4; hw[1] = a5; hw[2] = a6; hw[3] = a7;
        const bf16x8 paL = __builtin_bit_cast(bf16x8, lo);
        const bf16x8 paH = __builtin_bit_cast(bf16x8, hw);

        o0 = __builtin_amdgcn_mfma_f32_32x32x16_bf16(paL, vb[c * 4 + 0], o0, 0, 0, 0);
        o1 = __builtin_amdgcn_mfma_f32_32x32x16_bf16(paL, vb[c * 4 + 1], o1, 0, 0, 0);
        o0 = __builtin_amdgcn_mfma_f32_32x32x16_bf16(paH, vb[c * 4 + 2], o0, 0, 0, 0);
        o1 = __builtin_amdgcn_mfma_f32_32x32x16_bf16(paH, vb[c * 4 + 3], o1, 0, 0, 0);
    }
    __builtin_amdgcn_s_setprio(0);
}

// ---------------------------------------------------------------------------
// Causal flash attention, DBUF-pairwise pipeline (R19/R20, verified).
// grid 1024 (heavy-first: qt = 31 - bid/32), block 128 = 2 warps x 32 q-rows.
// ---------------------------------------------------------------------------
__global__ __launch_bounds__(128) void attn_kernel(
    const short* __restrict__ Q, const short* __restrict__ K,
    const short* __restrict__ VtG, short* __restrict__ O) {
    __shared__ short KbA[4096], VbA[4096], KbB[4096], VbB[4096];  // 32 KB

    const int tid = threadIdx.x, lane = tid & 63, wid = tid >> 6;
    const int l31 = lane & 31, hi = lane >> 5;
    const int bid = blockIdx.x;
    const int qt = 31 - (bid >> 5);
    const int bh = bid & 31;
    const int b = bh >> 4, h = bh & 15;
    const size_t base = (size_t)b * 2048 * 1024 + (size_t)h * 64;
    const short* Qp = Q + base;
    const short* Kp = K + base;
    const short* Vp = VtG + (size_t)(h * 64) * 4096 + (size_t)b * 2048;
    short* Op = O + base;

    const int q0w = qt * 64 + wid * 32;
    const int qrow = q0w + l31;

    const int srw = lane >> 3;
    const int swc = ((lane & 7) ^ srw) * 8;
    const short* kSrc = Kp + (size_t)srw * 1024 + swc;
    const short* vSrc = Vp + (size_t)srw * 4096 + swc;
    const int cc0 = wid * 4;

    const int nt = qt + 1;

#define ISS(i, Ksb, Vsb)                                                       \
    if ((i) < nt) {                                                            \
        const int kv0i = (i) * 64;                                             \
        _Pragma("unroll")                                                      \
        for (int c = 0; c < 4; ++c) {                                          \
            const int cc = cc0 + c;                                            \
            gload16(kSrc + (size_t)(kv0i + cc * 8) * 1024, (Ksb) + cc * 512);  \
            gload16(vSrc + (size_t)(cc * 8) * 4096 + kv0i, (Vsb) + cc * 512);  \
        }                                                                      \
    }

    // ---- prologue: stage tiles 0,1 ----
    ISS(0, KbA, VbA); ISS(1, KbB, VbB);

    bf16x8 qf[4];
#pragma unroll
    for (int ds = 0; ds < 4; ++ds)
        qf[ds] = ld8(Qp + (size_t)qrow * 1024 + ds * 16 + hi * 8);

    asm volatile("s_waitcnt vmcnt(0)" ::: "memory");
    __builtin_amdgcn_s_barrier();
    __builtin_amdgcn_sched_barrier(0);

    f32x16 o0 = 0.0f, o1 = 0.0f;
    float l = 0.0f;
    bf16x8 kf0[8], vb0[8], kf1[8], vb1[8];

    int t = 0;
#pragma unroll 1
    while (t < nt) {
        read_frags(KbA, VbA, l31, hi, kf0, vb0);
        if (t + 1 < nt) read_frags(KbB, VbB, l31, hi, kf1, vb1);
        asm volatile("s_waitcnt lgkmcnt(0)" ::: "memory");
        __builtin_amdgcn_s_barrier();
        __builtin_amdgcn_sched_barrier(0);
        ISS(t + 2, KbA, VbA);
        ISS(t + 3, KbB, VbB);
        __builtin_amdgcn_sched_barrier(0);
        if (t == nt - 1)
            attn_tile_r<true>(t * 64, kf0, vb0, qf, o0, o1, l, qrow, hi);
        else
            attn_tile_r<false>(t * 64, kf0, vb0, qf, o0, o1, l, qrow, hi);
        if (t + 1 < nt) {
            if (t + 1 == nt - 1)
                attn_tile_r<true>((t + 1) * 64, kf1, vb1, qf, o0, o1, l, qrow, hi);
            else
                attn_tile_r<false>((t + 1) * 64, kf1, vb1, qf, o0, o1, l, qrow, hi);
        }
        t += 2;
        if (t < nt) {
            asm volatile("s_waitcnt vmcnt(0)" ::: "memory");
            __builtin_amdgcn_s_barrier();
            __builtin_amdgcn_sched_barrier(0);
        }
    }
#undef ISS

    const float lt = l + __shfl_xor(l, 32, 64);
    const float il = 1.0f / lt;
#pragma unroll
    for (int r = 0; r < 16; ++r) {
        const int cr = (r & 3) + 8 * (r >> 2) + 4 * hi;
        const float s = __shfl(il, cr, 64);
        const size_t row = (size_t)(q0w + cr) * 1024;
        Op[row + l31]      = f2bfs(o0[r] * s);
        Op[row + 32 + l31] = f2bfs(o1[r] * s);
    }
}

// ---------------------------------------------------------------------------
extern "C" void kernel_launch(void* const* d_in, const int* in_sizes, int n_in,
                              void* d_out, int out_size, void* d_ws, size_t ws_size,
                              hipStream_t stream) {
    const float* x  = (const float*)d_in[0];
    const float* Wq = (const float*)d_in[1];
    const float* Wk = (const float*)d_in[2];
    const float* Wv = (const float*)d_in[3];
    const float* Wo = (const float*)d_in[4];

    short* wb  = (short*)d_ws;                 // 4 x 1M shorts (8 MB)
    short* Qw  = wb + (size_t)4 * 1048576;     // 8 MB (attn out aliases this)
    short* Kw  = Qw + (size_t)4194304;         // 8 MB
    short* Vtw = Kw + (size_t)4194304;         // 8 MB  (VtG[1024][4096])
    short* xb  = (short*)d_out;                // bf16 x lives in d_out[0:8MB]

    convert_kernel<<<4096, 256, 0, stream>>>(x, Wq, Wk, Wv, Wo, xb, wb);
    gemm_qkv_kernel<<<dim3(32, 24), 256, 0, stream>>>(xb, wb, Qw, Kw, Vtw);
    attn_kernel<<<1024, 128, 0, stream>>>(Qw, Kw, Vtw, Qw);
    gemm_wo_kernel<<<dim3(64, 8), 256, 0, stream>>>(Qw, wb + (size_t)3 * 1048576, (float*)d_out);
}